// Round 20
// baseline (3980.493 us; speedup 1.0000x reference)
//
#include <hip/hip_runtime.h>
#include <hip/hip_fp16.h>

#define BB 8
#define SS 2048
#define EE 1024
#define NHH 4
#define DHH 256

typedef _Float16 f16x2 __attribute__((ext_vector_type(2)));
typedef _Float16 f16x8 __attribute__((ext_vector_type(8)));
typedef float f32x4 __attribute__((ext_vector_type(4)));

__device__ __forceinline__ __half2 u2h2(unsigned int u) {
  union { unsigned int u; __half2 h; } c; c.u = u; return c.h;
}
__device__ __forceinline__ unsigned int h2u(__half2 h) {
  union { unsigned int u; __half2 h; } c; c.h = h; return c.u;
}
__device__ __forceinline__ f16x2 u2f(unsigned int u) {
  union { unsigned int u; f16x2 f; } c; c.u = u; return c.f;
}
__device__ __forceinline__ unsigned int pack2(float a, float b) {
  f16x2 f; f.x = (_Float16)a; f.y = (_Float16)b;
  union { f16x2 f; unsigned int u; } c; c.f = f; return c.u;
}
__device__ __forceinline__ float fdot2u(unsigned int w, unsigned int y, float acc) {
#if __has_builtin(__builtin_amdgcn_fdot2)
  return __builtin_amdgcn_fdot2(u2f(w), u2f(y), acc, false);
#else
  __half2 a = u2h2(w), b = u2h2(y);
  return acc + __low2float(a) * __low2float(b) + __high2float(a) * __high2float(b);
#endif
}

// ---------------------------------------------------------------------------
// MEGA kernel (round-19 structure, 64-step gating granularity):
//   gemm: 2048 WGs x 2 tiles, mt-major; prog[c] c=0..31 counts tiles for
//         s-chunk of 64 steps (target 128).
//   scan: 32 WGs (r6 structure); gates on prog at 64-step boundaries.
//   GN:   256 WGs, each (b, 64-step chunk); waits on sprog[c*8+b] (target 4).
// All spins have escape hatches. Dynamic LDS 132096 B.
// ---------------------------------------------------------------------------
__global__
__attribute__((amdgpu_flat_work_group_size(512, 512), amdgpu_waves_per_eu(1)))
void mega(
    const float* __restrict__ x, const float* __restrict__ conv_w,
    const float* __restrict__ conv_b,
    const float* __restrict__ fgw, const float* __restrict__ igw,
    const float* __restrict__ zgw, const float* __restrict__ ogw,
    const float* __restrict__ rk, const float* __restrict__ rb,
    const float* __restrict__ gnw,
    __half* __restrict__ gx, float* __restrict__ out,
    unsigned int* __restrict__ prog, unsigned int* __restrict__ sprog)
{
  extern __shared__ unsigned char sm[];
  const int bid = blockIdx.x;
  const int tid = threadIdx.x;

  if (bid >= 32 && bid < 32 + 2048) {
    // =============================== GEMM path ===============================
    const int half = tid >> 8, ltid = tid & 255;
    const int ti = (bid - 32) * 2 + half;          // 0..4095
    const int mtg = ti >> 4;                       // 0..255
    const int rest = ti & 15;
    const int nt2 = rest >> 2, h = rest & 3;
    const int s0 = mtg << 3;
    const int n0 = nt2 << 7;

    unsigned char* base = sm + half * 42368;
    float* Xs = (float*)base;                          // [8][11][33] f32
    __half* As = (__half*)(base + 11648);              // [2][64][40]
    __half* Bs = (__half*)(base + 11648 + 10240);      // [2][128][40]

    const float* W0 = (n0 < 256) ? fgw : igw;
    const float* W1 = (n0 < 256) ? zgw : ogw;
    const int oobase = n0 & 255;

    const int lw = (tid >> 6) & 3, l = tid & 63;
    const int lrow = l & 15, kq = l >> 4;
    const int koff = kq << 3;

    f32x4 acc[2][2][4] = {};

    for (int d0 = 0; d0 < DHH; d0 += 32) {
      const int ebase = h * DHH + d0;

      for (int i = ltid; i < 8 * 11 * 32; i += 256) {
        int kk = i & 31, rest2 = i >> 5;
        int b = rest2 / 11, si = rest2 - b * 11;
        int sg = s0 - 3 + si;
        float v = 0.f;
        if (sg >= 0) v = x[((size_t)b * SS + sg) * EE + ebase + kk];
        Xs[(b * 11 + si) * 33 + kk] = v;
      }
      for (int i = ltid; i < 2 * 128 * 32; i += 256) {
        int p = i >> 12;
        int rem = i & 4095;
        int col = rem >> 5, k = rem & 31;
        const float* Wp = p ? W1 : W0;
        int oo = oobase + col;
        Bs[(p * 128 + col) * 40 + k] =
            __float2half(Wp[((size_t)h * DHH + oo) * DHH + d0 + k]);
      }
      __syncthreads();

      for (int i = ltid; i < 2 * 64 * 32; i += 256) {
        int p = i >> 11;
        int rem = i & 2047;
        int kk = rem & 31, r = rem >> 5;
        int sl = r >> 3, b = r & 7;
        if (p == 0) {
          int e = ebase + kk;
          float xc = conv_b[e];
          xc = fmaf(Xs[(b * 11 + sl + 0) * 33 + kk], conv_w[0 * EE + e], xc);
          xc = fmaf(Xs[(b * 11 + sl + 1) * 33 + kk], conv_w[1 * EE + e], xc);
          xc = fmaf(Xs[(b * 11 + sl + 2) * 33 + kk], conv_w[2 * EE + e], xc);
          xc = fmaf(Xs[(b * 11 + sl + 3) * 33 + kk], conv_w[3 * EE + e], xc);
          float sg = 1.f / (1.f + __expf(-xc));
          As[(0 * 64 + r) * 40 + kk] = __float2half(xc * sg);
        } else {
          As[(1 * 64 + r) * 40 + kk] = __float2half(Xs[(b * 11 + sl + 3) * 33 + kk]);
        }
      }
      __syncthreads();

#pragma unroll
      for (int p = 0; p < 2; ++p) {
#pragma unroll
        for (int ct = 0; ct < 2; ++ct) {
          f16x8 bfrag = *(const f16x8*)&Bs[(p * 128 + lw * 32 + ct * 16 + lrow) * 40 + koff];
#pragma unroll
          for (int mtl = 0; mtl < 4; ++mtl) {
            f16x8 afrag = *(const f16x8*)&As[(p * 64 + mtl * 16 + lrow) * 40 + koff];
            acc[p][ct][mtl] =
                __builtin_amdgcn_mfma_f32_16x16x32_f16(afrag, bfrag, acc[p][ct][mtl], 0, 0, 0);
          }
        }
      }
      __syncthreads();
    }

#pragma unroll
    for (int p = 0; p < 2; ++p) {
#pragma unroll
      for (int ct = 0; ct < 2; ++ct) {
#pragma unroll
        for (int mtl = 0; mtl < 4; ++mtl) {
#pragma unroll
          for (int j = 0; j < 4; ++j) {
            int row_loc = mtl * 16 + kq * 4 + j;
            int grow = mtg * 64 + row_loc;
            int colg = n0 + lw * 32 + ct * 16 + lrow;
            gx[(size_t)grow * 4096 + h * 1024 + p * 512 + colg] =
                __float2half(acc[p][ct][mtl][j]);
          }
        }
      }
    }

    __syncthreads();   // all stores of both halves drained (vmcnt 0)
    if (ltid == 0)
      __hip_atomic_fetch_add(&prog[mtg >> 3], 1u,
                             __ATOMIC_RELEASE, __HIP_MEMORY_SCOPE_AGENT);
    return;
  }

  if (bid < 32) {
    // =============================== SCAN path ===============================
    uint4* wl4   = (uint4*)sm;                      // [16][512]
    __half* ypub = (__half*)(sm + 131072);          // [2][256]

    const int t = tid;
    const int b = bid >> 2, h = bid & 3;
    const int d = t >> 1, par = t & 1;
    const int kbase = par << 7;
    const float* Rh = rk + (size_t)h * DHH * 1024;

    unsigned int wv[3][64];
#pragma unroll
    for (int g = 0; g < 3; ++g) {
      const int col = g * 256 + d;
#pragma unroll
      for (int pp = 0; pp < 64; ++pp) {
        int k = kbase + 2 * pp;
        wv[g][pp] = pack2(Rh[(size_t)k * 1024 + col], Rh[(size_t)(k + 1) * 1024 + col]);
      }
    }
    {
      const int col = 3 * 256 + d;
      for (int q = 0; q < 16; ++q) {
        uint4 u;
        int k = kbase + 8 * q;
        u.x = pack2(Rh[(size_t)(k + 0) * 1024 + col], Rh[(size_t)(k + 1) * 1024 + col]);
        u.y = pack2(Rh[(size_t)(k + 2) * 1024 + col], Rh[(size_t)(k + 3) * 1024 + col]);
        u.z = pack2(Rh[(size_t)(k + 4) * 1024 + col], Rh[(size_t)(k + 5) * 1024 + col]);
        u.w = pack2(Rh[(size_t)(k + 6) * 1024 + col], Rh[(size_t)(k + 7) * 1024 + col]);
        wl4[q * 512 + t] = u;
      }
    }

    float rbv[4];
#pragma unroll
    for (int g = 0; g < 4; ++g) rbv[g] = rb[h * 1024 + g * 256 + d];

    float c = 0.f, n = 0.f, m = 0.f;
    if (t < 256) { ypub[t] = __float2half(0.f); ypub[256 + t] = __float2half(0.f); }
    __syncthreads();

    // wait for gemm chunk 0 (steps 0..63)
    if (t == 0) {
      int it = 0;
      while (__hip_atomic_load(&prog[0], __ATOMIC_ACQUIRE,
                               __HIP_MEMORY_SCOPE_AGENT) < 128u) {
        __builtin_amdgcn_s_sleep(4);
        if (++it > (1 << 21)) break;
      }
    }
    __syncthreads();
    int curc = 0;

    int cur = 0;
    const __half* pg = gx + ((size_t)b * NHH + h) * 1024;
    float cx[4];
#pragma unroll
    for (int g = 0; g < 4; ++g) cx[g] = __half2float(pg[g * 256 + d]);
    const size_t out_base = ((size_t)b * SS) * EE + h * DHH + d;

    for (int st = 0; st < SS; ++st) {
      // gate on gemm progress for step st+1 (the in-loop prefetch target)
      {
        int needc = ((st + 1 < SS) ? st + 1 : SS - 1) >> 6;
        if (needc != curc) {
          if (t == 0) {
            int it = 0;
            while (__hip_atomic_load(&prog[needc], __ATOMIC_ACQUIRE,
                                     __HIP_MEMORY_SCOPE_AGENT) < 128u) {
              __builtin_amdgcn_s_sleep(4);
              if (++it > (1 << 21)) break;
            }
          }
          __syncthreads();
          curc = needc;
        }
      }

      const __half* pn = pg + ((st + 1 < SS) ? (size_t)(BB * NHH * 1024) : 0);
      __half nx[4];
#pragma unroll
      for (int g = 0; g < 4; ++g) nx[g] = pn[g * 256 + d];

      const uint4* yv = (const uint4*)(ypub + cur * 256) + (par << 4);
      float aA0 = 0.f, aB0 = 0.f, aA1 = 0.f, aB1 = 0.f;
      float aA2 = 0.f, aB2 = 0.f, aA3 = 0.f, aB3 = 0.f;
#pragma unroll
      for (int j = 0; j < 16; ++j) {
        uint4 yq = yv[j];
        uint4 wq = wl4[j * 512 + t];
        aA0 = fdot2u(wv[0][4 * j + 0], yq.x, aA0);
        aA1 = fdot2u(wv[1][4 * j + 0], yq.x, aA1);
        aA2 = fdot2u(wv[2][4 * j + 0], yq.x, aA2);
        aA3 = fdot2u(wq.x,             yq.x, aA3);
        aB0 = fdot2u(wv[0][4 * j + 1], yq.y, aB0);
        aB1 = fdot2u(wv[1][4 * j + 1], yq.y, aB1);
        aB2 = fdot2u(wv[2][4 * j + 1], yq.y, aB2);
        aB3 = fdot2u(wq.y,             yq.y, aB3);
        aA0 = fdot2u(wv[0][4 * j + 2], yq.z, aA0);
        aA1 = fdot2u(wv[1][4 * j + 2], yq.z, aA1);
        aA2 = fdot2u(wv[2][4 * j + 2], yq.z, aA2);
        aA3 = fdot2u(wq.z,             yq.z, aA3);
        aB0 = fdot2u(wv[0][4 * j + 3], yq.w, aB0);
        aB1 = fdot2u(wv[1][4 * j + 3], yq.w, aB1);
        aB2 = fdot2u(wv[2][4 * j + 3], yq.w, aB2);
        aB3 = fdot2u(wq.w,             yq.w, aB3);
      }

      float part0 = aA0 + aB0, part1 = aA1 + aB1;
      float part2 = aA2 + aB2, part3 = aA3 + aB3;
      float raw0 = part0 + __shfl_xor(part0, 1) + cx[0] + rbv[0];
      float raw1 = part1 + __shfl_xor(part1, 1) + cx[1] + rbv[1];
      float raw2 = part2 + __shfl_xor(part2, 1) + cx[2] + rbv[2];
      float raw3 = part3 + __shfl_xor(part3, 1) + cx[3] + rbv[3];

      float iv = raw0, fv = raw1, zv = raw2, ov = raw3;
      float ea = __expf(-fabsf(fv));
      float ls = fminf(fv, 0.f) - __logf(1.f + ea);      // log_sigmoid(fv)
      float lfm = m + ls;
      float mn = fmaxf(iv, lfm);
      float ig = __expf(iv - mn);
      float fg = __expf(lfm - mn);
      float pz = __expf(-2.f * fabsf(zv));
      float tmag = __fdividef(1.f - pz, 1.f + pz);
      float th = (zv < 0.f) ? -tmag : tmag;              // tanh(zv)
      c = fg * c + ig * th;
      n = fg * n + ig;
      float og = __fdividef(1.f, 1.f + __expf(-ov));     // sigmoid(ov)
      float y = og * __fdividef(c, n);
      m = mn;

      if (par == 0) {
        out[out_base + (size_t)st * EE] = y;
        ypub[(cur ^ 1) * 256 + d] = __float2half(y);
      }
      __syncthreads();

      // publish chunk completion for GN (once per 64 steps)
      if ((st & 63) == 63 && t == 0) {
        __hip_atomic_fetch_add(&sprog[(st >> 6) * 8 + b], 1u,
                               __ATOMIC_RELEASE, __HIP_MEMORY_SCOPE_AGENT);
      }

      cur ^= 1;
      pg = pn;
#pragma unroll
      for (int g = 0; g < 4; ++g) cx[g] = __half2float(nx[g]);
    }
    return;
  }

  // =============================== GN path ===============================
  {
    const int g = bid - (32 + 2048);      // 0..255
    const int cchunk = g >> 3, b = g & 7; // 32 chunks x 8 batches
    const int half = tid >> 8, tt = tid & 255;

    if (tid == 0) {
      int it = 0;
      while (__hip_atomic_load(&sprog[cchunk * 8 + b], __ATOMIC_ACQUIRE,
                               __HIP_MEMORY_SCOPE_AGENT) < 4u) {
        __builtin_amdgcn_s_sleep(16);
        if (++it > (1 << 21)) break;
      }
    }
    __syncthreads();

    for (int sr = 0; sr < 64; sr += 2) {
      const int s = cchunk * 64 + sr + half;
      const size_t row = (size_t)b * SS + s;
      float4 v = ((const float4*)out)[row * 256 + tt];
      float sacc = v.x + v.y + v.z + v.w;
      float qacc = v.x * v.x + v.y * v.y + v.z * v.z + v.w * v.w;
#pragma unroll
      for (int mask = 1; mask < 64; mask <<= 1) {
        sacc += __shfl_xor(sacc, mask, 64);
        qacc += __shfl_xor(qacc, mask, 64);
      }
      float mu = sacc * (1.f / 256.f);
      float var = qacc * (1.f / 256.f) - mu * mu;
      float rs = rsqrtf(var + 1e-5f);
      float4 gw = ((const float4*)gnw)[tt];
      float4 o;
      o.x = (v.x - mu) * rs * gw.x;
      o.y = (v.y - mu) * rs * gw.y;
      o.z = (v.z - mu) * rs * gw.z;
      o.w = (v.w - mu) * rs * gw.w;
      ((float4*)out)[row * 256 + tt] = o;
    }
  }
}

extern "C" void kernel_launch(void* const* d_in, const int* in_sizes, int n_in,
                              void* d_out, int out_size, void* d_ws, size_t ws_size,
                              hipStream_t stream) {
  const float* x      = (const float*)d_in[0];
  const float* conv_w = (const float*)d_in[1];
  const float* conv_b = (const float*)d_in[2];
  const float* fgw    = (const float*)d_in[3];
  const float* igw    = (const float*)d_in[4];
  const float* zgw    = (const float*)d_in[5];
  const float* ogw    = (const float*)d_in[6];
  const float* rk     = (const float*)d_in[7];
  const float* rb     = (const float*)d_in[8];
  const float* gnw    = (const float*)d_in[9];
  float* out = (float*)d_out;

  __half* gx = (__half*)d_ws;                                      // 134217728 B
  unsigned int* prog  = (unsigned int*)((char*)d_ws + 134217728);  // 128 B (32 ctr)
  unsigned int* sprog = (unsigned int*)((char*)d_ws + 134217728 + 1024); // 1024 B

  (void)hipMemsetAsync(prog, 0, 8192, stream);

  const int lds = 132096;
  (void)hipFuncSetAttribute(reinterpret_cast<const void*>(mega),
                            hipFuncAttributeMaxDynamicSharedMemorySize, lds);
  mega<<<32 + 2048 + 256, 512, lds, stream>>>(
      x, conv_w, conv_b, fgw, igw, zgw, ogw, rk, rb, gnw, gx, out, prog, sprog);
}

// Round 21
// 3709.195 us; speedup vs baseline: 1.0731x; 1.0731x over previous
//
#include <hip/hip_runtime.h>
#include <hip/hip_fp16.h>

#define BB 8
#define SS 2048
#define EE 1024
#define NHH 4
#define DHH 256

typedef _Float16 f16x2 __attribute__((ext_vector_type(2)));
typedef _Float16 f16x8 __attribute__((ext_vector_type(8)));
typedef float f32x4 __attribute__((ext_vector_type(4)));

__device__ __forceinline__ __half2 u2h2(unsigned int u) {
  union { unsigned int u; __half2 h; } c; c.u = u; return c.h;
}
__device__ __forceinline__ unsigned int h2u(__half2 h) {
  union { unsigned int u; __half2 h; } c; c.h = h; return c.u;
}
__device__ __forceinline__ f16x2 u2f(unsigned int u) {
  union { unsigned int u; f16x2 f; } c; c.u = u; return c.f;
}
__device__ __forceinline__ unsigned int pack2(float a, float b) {
  f16x2 f; f.x = (_Float16)a; f.y = (_Float16)b;
  union { f16x2 f; unsigned int u; } c; c.f = f; return c.u;
}
__device__ __forceinline__ float fdot2u(unsigned int w, unsigned int y, float acc) {
#if __has_builtin(__builtin_amdgcn_fdot2)
  return __builtin_amdgcn_fdot2(u2f(w), u2f(y), acc, false);
#else
  __half2 a = u2h2(w), b = u2h2(y);
  return acc + __low2float(a) * __low2float(b) + __high2float(a) * __high2float(b);
#endif
}

// ---------------------------------------------------------------------------
// MEGA kernel (round-19 verbatim — session best 3719 us): gemm (2048 WGs,
// 2 tiles each) + scan (32 WGs) + groupnorm (64 WGs) in ONE dispatch,
// overlapped via coarse chunk counters.
//   prog[c]  (c=0..7): gemm tiles done for s-chunk c (target 512)
//   sprog[c*8+b]: scan WGs of batch b done with chunk c (target 4 heads)
// Scan waits 8 times total (not per-step); GN waits once per (b,c).
// All spins have escape hatches -> no hangs, worst case absmax failure.
// Dynamic LDS 132096 B (scan layout; gemm uses 84736 of it; GN none).
// ---------------------------------------------------------------------------
__global__
__attribute__((amdgpu_flat_work_group_size(512, 512), amdgpu_waves_per_eu(1)))
void mega(
    const float* __restrict__ x, const float* __restrict__ conv_w,
    const float* __restrict__ conv_b,
    const float* __restrict__ fgw, const float* __restrict__ igw,
    const float* __restrict__ zgw, const float* __restrict__ ogw,
    const float* __restrict__ rk, const float* __restrict__ rb,
    const float* __restrict__ gnw,
    __half* __restrict__ gx, float* __restrict__ out,
    unsigned int* __restrict__ prog, unsigned int* __restrict__ sprog)
{
  extern __shared__ unsigned char sm[];
  const int bid = blockIdx.x;
  const int tid = threadIdx.x;

  if (bid >= 32 && bid < 32 + 2048) {
    // =============================== GEMM path ===============================
    // 512-thr block = two independent 256-thr halves, each one tile (mt,nt2,h).
    // mt-major tile order -> low-s chunks complete first.
    const int half = tid >> 8, ltid = tid & 255;
    const int ti = (bid - 32) * 2 + half;          // 0..4095
    const int mtg = ti >> 4;                       // 0..255
    const int rest = ti & 15;
    const int nt2 = rest >> 2, h = rest & 3;
    const int s0 = mtg << 3;
    const int n0 = nt2 << 7;

    unsigned char* base = sm + half * 42368;
    float* Xs = (float*)base;                          // [8][11][33] f32
    __half* As = (__half*)(base + 11648);              // [2][64][40]
    __half* Bs = (__half*)(base + 11648 + 10240);      // [2][128][40]

    const float* W0 = (n0 < 256) ? fgw : igw;
    const float* W1 = (n0 < 256) ? zgw : ogw;
    const int oobase = n0 & 255;

    const int lw = (tid >> 6) & 3, l = tid & 63;
    const int lrow = l & 15, kq = l >> 4;
    const int koff = kq << 3;

    f32x4 acc[2][2][4] = {};

    for (int d0 = 0; d0 < DHH; d0 += 32) {
      const int ebase = h * DHH + d0;

      for (int i = ltid; i < 8 * 11 * 32; i += 256) {
        int kk = i & 31, rest2 = i >> 5;
        int b = rest2 / 11, si = rest2 - b * 11;
        int sg = s0 - 3 + si;
        float v = 0.f;
        if (sg >= 0) v = x[((size_t)b * SS + sg) * EE + ebase + kk];
        Xs[(b * 11 + si) * 33 + kk] = v;
      }
      for (int i = ltid; i < 2 * 128 * 32; i += 256) {
        int p = i >> 12;
        int rem = i & 4095;
        int col = rem >> 5, k = rem & 31;
        const float* Wp = p ? W1 : W0;
        int oo = oobase + col;
        Bs[(p * 128 + col) * 40 + k] =
            __float2half(Wp[((size_t)h * DHH + oo) * DHH + d0 + k]);
      }
      __syncthreads();

      for (int i = ltid; i < 2 * 64 * 32; i += 256) {
        int p = i >> 11;
        int rem = i & 2047;
        int kk = rem & 31, r = rem >> 5;
        int sl = r >> 3, b = r & 7;
        if (p == 0) {
          int e = ebase + kk;
          float xc = conv_b[e];
          xc = fmaf(Xs[(b * 11 + sl + 0) * 33 + kk], conv_w[0 * EE + e], xc);
          xc = fmaf(Xs[(b * 11 + sl + 1) * 33 + kk], conv_w[1 * EE + e], xc);
          xc = fmaf(Xs[(b * 11 + sl + 2) * 33 + kk], conv_w[2 * EE + e], xc);
          xc = fmaf(Xs[(b * 11 + sl + 3) * 33 + kk], conv_w[3 * EE + e], xc);
          float sg = 1.f / (1.f + __expf(-xc));
          As[(0 * 64 + r) * 40 + kk] = __float2half(xc * sg);
        } else {
          As[(1 * 64 + r) * 40 + kk] = __float2half(Xs[(b * 11 + sl + 3) * 33 + kk]);
        }
      }
      __syncthreads();

#pragma unroll
      for (int p = 0; p < 2; ++p) {
#pragma unroll
        for (int ct = 0; ct < 2; ++ct) {
          f16x8 bfrag = *(const f16x8*)&Bs[(p * 128 + lw * 32 + ct * 16 + lrow) * 40 + koff];
#pragma unroll
          for (int mtl = 0; mtl < 4; ++mtl) {
            f16x8 afrag = *(const f16x8*)&As[(p * 64 + mtl * 16 + lrow) * 40 + koff];
            acc[p][ct][mtl] =
                __builtin_amdgcn_mfma_f32_16x16x32_f16(afrag, bfrag, acc[p][ct][mtl], 0, 0, 0);
          }
        }
      }
      __syncthreads();
    }

#pragma unroll
    for (int p = 0; p < 2; ++p) {
#pragma unroll
      for (int ct = 0; ct < 2; ++ct) {
#pragma unroll
        for (int mtl = 0; mtl < 4; ++mtl) {
#pragma unroll
          for (int j = 0; j < 4; ++j) {
            int row_loc = mtl * 16 + kq * 4 + j;
            int grow = mtg * 64 + row_loc;
            int colg = n0 + lw * 32 + ct * 16 + lrow;
            gx[(size_t)grow * 4096 + h * 1024 + p * 512 + colg] =
                __float2half(acc[p][ct][mtl][j]);
          }
        }
      }
    }

    __syncthreads();   // all stores of both halves drained (vmcnt 0)
    if (ltid == 0)
      __hip_atomic_fetch_add(&prog[mtg >> 5], 1u,
                             __ATOMIC_RELEASE, __HIP_MEMORY_SCOPE_AGENT);
    return;
  }

  if (bid < 32) {
    // =============================== SCAN path ===============================
    // round-6 structure verbatim (session-best 3.40 ms) + chunk gating.
    uint4* wl4   = (uint4*)sm;                      // [16][512]
    __half* ypub = (__half*)(sm + 131072);          // [2][256]

    const int t = tid;
    const int b = bid >> 2, h = bid & 3;
    const int d = t >> 1, par = t & 1;
    const int kbase = par << 7;
    const float* Rh = rk + (size_t)h * DHH * 1024;

    unsigned int wv[3][64];
#pragma unroll
    for (int g = 0; g < 3; ++g) {
      const int col = g * 256 + d;
#pragma unroll
      for (int pp = 0; pp < 64; ++pp) {
        int k = kbase + 2 * pp;
        wv[g][pp] = pack2(Rh[(size_t)k * 1024 + col], Rh[(size_t)(k + 1) * 1024 + col]);
      }
    }
    {
      const int col = 3 * 256 + d;
      for (int q = 0; q < 16; ++q) {
        uint4 u;
        int k = kbase + 8 * q;
        u.x = pack2(Rh[(size_t)(k + 0) * 1024 + col], Rh[(size_t)(k + 1) * 1024 + col]);
        u.y = pack2(Rh[(size_t)(k + 2) * 1024 + col], Rh[(size_t)(k + 3) * 1024 + col]);
        u.z = pack2(Rh[(size_t)(k + 4) * 1024 + col], Rh[(size_t)(k + 5) * 1024 + col]);
        u.w = pack2(Rh[(size_t)(k + 6) * 1024 + col], Rh[(size_t)(k + 7) * 1024 + col]);
        wl4[q * 512 + t] = u;
      }
    }

    float rbv[4];
#pragma unroll
    for (int g = 0; g < 4; ++g) rbv[g] = rb[h * 1024 + g * 256 + d];

    float c = 0.f, n = 0.f, m = 0.f;
    if (t < 256) { ypub[t] = __float2half(0.f); ypub[256 + t] = __float2half(0.f); }
    __syncthreads();

    // wait for gemm chunk 0 (covers gx steps 0..255)
    if (t == 0) {
      int it = 0;
      while (__hip_atomic_load(&prog[0], __ATOMIC_ACQUIRE,
                               __HIP_MEMORY_SCOPE_AGENT) < 512u) {
        __builtin_amdgcn_s_sleep(8);
        if (++it > (1 << 20)) break;
      }
    }
    __syncthreads();
    int curc = 0;

    int cur = 0;
    const __half* pg = gx + ((size_t)b * NHH + h) * 1024;
    float cx[4];
#pragma unroll
    for (int g = 0; g < 4; ++g) cx[g] = __half2float(pg[g * 256 + d]);
    const size_t out_base = ((size_t)b * SS) * EE + h * DHH + d;

    for (int st = 0; st < SS; ++st) {
      // gate on gemm progress for step st+1 (the in-loop prefetch target)
      {
        int needc = ((st + 1 < SS) ? st + 1 : SS - 1) >> 8;
        if (needc != curc) {
          if (t == 0) {
            int it = 0;
            while (__hip_atomic_load(&prog[needc], __ATOMIC_ACQUIRE,
                                     __HIP_MEMORY_SCOPE_AGENT) < 512u) {
              __builtin_amdgcn_s_sleep(8);
              if (++it > (1 << 20)) break;
            }
          }
          __syncthreads();
          curc = needc;
        }
      }

      const __half* pn = pg + ((st + 1 < SS) ? (size_t)(BB * NHH * 1024) : 0);
      __half nx[4];
#pragma unroll
      for (int g = 0; g < 4; ++g) nx[g] = pn[g * 256 + d];

      const uint4* yv = (const uint4*)(ypub + cur * 256) + (par << 4);
      float aA0 = 0.f, aB0 = 0.f, aA1 = 0.f, aB1 = 0.f;
      float aA2 = 0.f, aB2 = 0.f, aA3 = 0.f, aB3 = 0.f;
#pragma unroll
      for (int j = 0; j < 16; ++j) {
        uint4 yq = yv[j];
        uint4 wq = wl4[j * 512 + t];
        aA0 = fdot2u(wv[0][4 * j + 0], yq.x, aA0);
        aA1 = fdot2u(wv[1][4 * j + 0], yq.x, aA1);
        aA2 = fdot2u(wv[2][4 * j + 0], yq.x, aA2);
        aA3 = fdot2u(wq.x,             yq.x, aA3);
        aB0 = fdot2u(wv[0][4 * j + 1], yq.y, aB0);
        aB1 = fdot2u(wv[1][4 * j + 1], yq.y, aB1);
        aB2 = fdot2u(wv[2][4 * j + 1], yq.y, aB2);
        aB3 = fdot2u(wq.y,             yq.y, aB3);
        aA0 = fdot2u(wv[0][4 * j + 2], yq.z, aA0);
        aA1 = fdot2u(wv[1][4 * j + 2], yq.z, aA1);
        aA2 = fdot2u(wv[2][4 * j + 2], yq.z, aA2);
        aA3 = fdot2u(wq.z,             yq.z, aA3);
        aB0 = fdot2u(wv[0][4 * j + 3], yq.w, aB0);
        aB1 = fdot2u(wv[1][4 * j + 3], yq.w, aB1);
        aB2 = fdot2u(wv[2][4 * j + 3], yq.w, aB2);
        aB3 = fdot2u(wq.w,             yq.w, aB3);
      }

      float part0 = aA0 + aB0, part1 = aA1 + aB1;
      float part2 = aA2 + aB2, part3 = aA3 + aB3;
      float raw0 = part0 + __shfl_xor(part0, 1) + cx[0] + rbv[0];
      float raw1 = part1 + __shfl_xor(part1, 1) + cx[1] + rbv[1];
      float raw2 = part2 + __shfl_xor(part2, 1) + cx[2] + rbv[2];
      float raw3 = part3 + __shfl_xor(part3, 1) + cx[3] + rbv[3];

      float iv = raw0, fv = raw1, zv = raw2, ov = raw3;
      float ea = __expf(-fabsf(fv));
      float ls = fminf(fv, 0.f) - __logf(1.f + ea);      // log_sigmoid(fv)
      float lfm = m + ls;
      float mn = fmaxf(iv, lfm);
      float ig = __expf(iv - mn);
      float fg = __expf(lfm - mn);
      float pz = __expf(-2.f * fabsf(zv));
      float tmag = __fdividef(1.f - pz, 1.f + pz);
      float th = (zv < 0.f) ? -tmag : tmag;              // tanh(zv)
      c = fg * c + ig * th;
      n = fg * n + ig;
      float og = __fdividef(1.f, 1.f + __expf(-ov));     // sigmoid(ov)
      float y = og * __fdividef(c, n);
      m = mn;

      if (par == 0) {
        out[out_base + (size_t)st * EE] = y;
        ypub[(cur ^ 1) * 256 + d] = __float2half(y);
      }
      __syncthreads();

      // publish chunk completion for GN (once per 256 steps)
      if ((st & 255) == 255 && t == 0) {
        __hip_atomic_fetch_add(&sprog[(st >> 8) * 8 + b], 1u,
                               __ATOMIC_RELEASE, __HIP_MEMORY_SCOPE_AGENT);
      }

      cur ^= 1;
      pg = pn;
#pragma unroll
      for (int g = 0; g < 4; ++g) cx[g] = __half2float(nx[g]);
    }
    return;
  }

  // =============================== GN path ===============================
  {
    const int g = bid - (32 + 2048);      // 0..63
    const int cchunk = g >> 3, b = g & 7;
    const int half = tid >> 8, tt = tid & 255;

    if (tid == 0) {
      int it = 0;
      while (__hip_atomic_load(&sprog[cchunk * 8 + b], __ATOMIC_ACQUIRE,
                               __HIP_MEMORY_SCOPE_AGENT) < 4u) {
        __builtin_amdgcn_s_sleep(16);
        if (++it > (1 << 20)) break;
      }
    }
    __syncthreads();

    for (int sr = 0; sr < 256; sr += 2) {
      const int s = cchunk * 256 + sr + half;
      const size_t row = (size_t)b * SS + s;
      float4 v = ((const float4*)out)[row * 256 + tt];
      float sacc = v.x + v.y + v.z + v.w;
      float qacc = v.x * v.x + v.y * v.y + v.z * v.z + v.w * v.w;
#pragma unroll
      for (int mask = 1; mask < 64; mask <<= 1) {
        sacc += __shfl_xor(sacc, mask, 64);
        qacc += __shfl_xor(qacc, mask, 64);
      }
      float mu = sacc * (1.f / 256.f);
      float var = qacc * (1.f / 256.f) - mu * mu;
      float rs = rsqrtf(var + 1e-5f);
      float4 gw = ((const float4*)gnw)[tt];
      float4 o;
      o.x = (v.x - mu) * rs * gw.x;
      o.y = (v.y - mu) * rs * gw.y;
      o.z = (v.z - mu) * rs * gw.z;
      o.w = (v.w - mu) * rs * gw.w;
      ((float4*)out)[row * 256 + tt] = o;
    }
  }
}

extern "C" void kernel_launch(void* const* d_in, const int* in_sizes, int n_in,
                              void* d_out, int out_size, void* d_ws, size_t ws_size,
                              hipStream_t stream) {
  const float* x      = (const float*)d_in[0];
  const float* conv_w = (const float*)d_in[1];
  const float* conv_b = (const float*)d_in[2];
  const float* fgw    = (const float*)d_in[3];
  const float* igw    = (const float*)d_in[4];
  const float* zgw    = (const float*)d_in[5];
  const float* ogw    = (const float*)d_in[6];
  const float* rk     = (const float*)d_in[7];
  const float* rb     = (const float*)d_in[8];
  const float* gnw    = (const float*)d_in[9];
  float* out = (float*)d_out;

  __half* gx = (__half*)d_ws;                                      // 134217728 B
  unsigned int* prog  = (unsigned int*)((char*)d_ws + 134217728);  // 32 B
  unsigned int* sprog = (unsigned int*)((char*)d_ws + 134217728 + 128); // 256 B

  (void)hipMemsetAsync(prog, 0, 4096, stream);

  const int lds = 132096;
  (void)hipFuncSetAttribute(reinterpret_cast<const void*>(mega),
                            hipFuncAttributeMaxDynamicSharedMemorySize, lds);
  mega<<<32 + 2048 + 64, 512, lds, stream>>>(
      x, conv_w, conv_b, fgw, igw, zgw, ogw, rk, rb, gnw, gx, out, prog, sprog);
}